// Round 7
// baseline (348.458 us; speedup 1.0000x reference)
//
#include <hip/hip_runtime.h>

// Exact-order float32 arithmetic: numpy/jax evaluate left-to-right with no
// FMA contraction. hipcc defaults to -ffp-contract=fast, which would change
// rounding -> possible spike-time shift -> large voltage absmax error.
#pragma clang fp contract(off)

// R20 = R18 (best verified: 256-260 us/dispatch, absmax 0.0) with the
// ballot RESOLVE moved from SALU to VALU. Motivation (R14/R16/R19 post-
// mortems): single resident wave => every VALU->SALU->VALU crossing stall
// is fully exposed; R18's per-step cost (~149ns) is ~2x its pure VALU
// dependency latency. Here the ballot mask (uniform SGPR) is read DIRECTLY
// as a VOP3 SGPR operand by per-lane v_lshrrev_b32 (inline asm, same
// VOP3+SGPR pattern as the proven sel_mask), so the resolve
//   z2 = m.b0; z3 = m.b(1+z2); z4 = m.b(3+z3); z5 = m.b(5+z3);
//   selbit(lane) = m.b(selsh)   [selsh: L=31(always 0), EBN=0,
//                                IFN/TN=1+z2, MN=5+z3]
// runs entirely in the vector pipe (4-cyc forwarding), never crossing to
// the scalar ALU inside the step. Variant/fire selects are divergent
// ternaries (v_cmp + v_cndmask). Resolve formulas bit-identical to
// R13/R18. Anchor compares use full-mask equality (last_m == anchor_m),
// detection-equivalent to carry-bit equality: every ballot bit (incl.
// spec-junk bits) is a deterministic function of the repeating state.
// Everything else is R18 verbatim (lane map, speculative head/tail, fmaf
// exact fusion, batched float4 flush, rolling-40 + Brent detection,
// fill_cycle).
// Lane map (wave 0):
//   0   : LLBN (no speculation: I2 depends only on prev-step bits)
//   1,2 : EBN  speculating z2 = 0,1
//   3,4 : IFN  speculating z3 = 0,1
//   5,6 : TN   speculating z3 = 0,1   (known z5p folded into candidates)
//   7,8 : MN   speculating z5 = 0,1

// r = sm >> amt, computed on the VALU (amt per-lane VGPR, sm uniform SGPR).
// VOP3 form, 1 SGPR read — legal; output treated divergent by the compiler,
// keeping the downstream resolve in the vector pipe.
__device__ __forceinline__ int vshr(unsigned sm, int amt) {
    int r;
    asm("v_lshrrev_b32 %0, %1, %2" : "=v"(r) : "v"(amt), "s"(sm));
    return r;
}

__global__ __launch_bounds__(256) void net_sim(const float* __restrict__ mat,
                                               const float* __restrict__ w,
                                               float* __restrict__ out,
                                               int* __restrict__ ws,
                                               int T) {
    __shared__ double red[256];
    const int tid = threadIdx.x;

    // ---- z_plus = sum(input_mat * w0), f32 products accumulated in f64 ----
    const float w0 = w[0];
    double s = 0.0;
    for (int i = tid; i < 127 * 127; i += 256) {
        float p = mat[i] * w0;   // elementwise product rounded to f32 (as ref)
        s += (double)p;
    }
    red[tid] = s;
    __syncthreads();
    #pragma unroll
    for (int off = 128; off > 0; off >>= 1) {
        if (tid < off) red[tid] += red[tid + off];
        __syncthreads();
    }
    if (tid >= 9) return;   // 9 lanes of wave 0 continue; no more barriers

    const float z_plus = (float)red[0];

    const float w2 = w[2], w3 = w[3], w5 = w[5], w6 = w[6], w7 = w[7],
                w8 = w[8], w9 = w[9], w10 = w[10], w11 = w[11];
    const float zp_w1 = z_plus * w[1];
    const float zp_w4 = z_plus * w[4];

    // Validated constant-I set (R2..R18, absmax 0.0). z*w is exactly +0.0f
    // or w; x + (+0.0f) == x for the values involved.
    const float I2_00 = w2 * (zp_w1 - 0.0f) + w3 * 0.0f;   // (z2p, z4p)
    const float I2_10 = w2 * (zp_w1 - 0.0f) + w3 * 1.0f;
    const float I2_01 = w2 * (zp_w1 - w7)   + w3 * 0.0f;
    const float I2_11 = w2 * (zp_w1 - w7)   + w3 * 1.0f;
    const float I3_0  = zp_w4 + 0.0f * w5;
    const float I3_1  = zp_w4 + 1.0f * w5;
    const float I4_0  = 0.0f * w6;
    const float I4_1  = 1.0f * w6;
    const float I5_00 = w9 * (0.0f * w8) + w10 * 0.0f;     // (z3, z5p)
    const float I5_10 = w9 * (1.0f * w8) + w10 * 0.0f;
    const float I5_01 = w9 * (0.0f * w8) + w10 * 1.0f;
    const float I5_11 = w9 * (1.0f * w8) + w10 * 1.0f;
    const float I6_0  = 0.0f * w11;
    const float I6_1  = 1.0f * w11;

    const int lane = tid;  // 0..8
    const int g = lane == 0 ? 0 : lane <= 2 ? 1 : lane <= 4 ? 2 : lane <= 6 ? 3 : 4;

    // per-lane params; ka = float(TAU*DT*a) computed in f64 like Python
    const float ka = lane == 0 ? (float)(0.25 * 0.1) : (float)(0.25 * 0.02);
    const float b  = lane == 0 ? -0.075f : (g == 3 ? 0.2f : 0.25f);
    const float c  = g <= 1 ? -55.0f : -65.0f;
    const float d  = g == 1 ? 0.05f : 6.0f;
    float v = g == 0 ? -60.0f : (g == 3 ? -70.0f : -64.0f);
    float u = g == 0 ? 4.5f   : (g == 3 ? -14.0f : -16.0f);

    // candidate-I vectors: variant0/variant1 per group, for z5p=0(a)/1(b).
    const float C0a = g == 0 ? I2_00 : g == 1 ? I3_0 : g == 2 ? I4_0
                    : g == 3 ? I5_00 : I6_0;
    const float C0b = g == 0 ? I2_00 : g == 1 ? I3_0 : g == 2 ? I4_0
                    : g == 3 ? I5_01 : I6_0;
    const float C1a = g == 1 ? I3_1 : g == 2 ? I4_1 : g == 3 ? I5_10
                    : g == 4 ? I6_1 : 0.0f;
    const float C1b = g == 1 ? I3_1 : g == 2 ? I4_1 : g == 3 ? I5_11
                    : g == 4 ? I6_1 : 0.0f;

    const bool is_lane0  = (lane == 0);
    const bool spec_var1 = (lane == 2) | (lane == 4) | (lane == 6) | (lane == 8);
    const bool le2 = (lane <= 2);          // L/EBN group (loop-invariant)
    const bool ge7 = (lane >= 7);          // MN group
    const int  l0base = is_lane0 ? 31 : 0; // lane0: bit31 of m == 0 always

    float* __restrict__ psp = out + g * T;           // spikes row
    float* __restrict__ pvv = out + 5 * T + g * T;   // volts row

    // prev-step bits as per-lane (divergent) ints -> prep stays on VALU
    int z2v = 0, z4v = 0, z5v = 0;
    unsigned last_m = 0;   // uniform SGPR copy of the latest ballot mask

    // ---- cycle-detection: rolling-40 anchor + Brent pow-2 fallback ----
    float rav = 0.0f, rau = 0.0f; unsigned ra_m = 0; int ra_t = -1;
    float cav = 0.0f, cau = 0.0f; unsigned ca_m = 0; int ca_t = -1;
    int next_coarse = 8;
    int t_det = -1, Pf = 0;
    int blk5 = 0;   // t/8 mod 5; 0 <=> t % 40 == 0

    float zb[8], vb[8];

    int t = 0;
    for (; t + 8 <= T; t += 8) {
        // ---- block top: anchor compares / refresh (R9 semantics; carry
        // bits replaced by full last-ballot-mask equality — equivalent) ----
        if (blk5 == 0) {
            if (ra_t >= 0) {
                unsigned long long mv =
                    __ballot(__float_as_uint(v) == __float_as_uint(rav));
                unsigned long long mu =
                    __ballot(__float_as_uint(u) == __float_as_uint(rau));
                if (((mv & mu) & 0x1FFull) == 0x1FFull && last_m == ra_m) {
                    t_det = t; Pf = t - ra_t;   // Pf == 40
                    break;
                }
            }
            if (t) { rav = v; rau = u; ra_m = last_m; ra_t = t; }
        } else if (ca_t >= 0) {
            unsigned long long mv =
                __ballot(__float_as_uint(v) == __float_as_uint(cav));
            unsigned long long mu =
                __ballot(__float_as_uint(u) == __float_as_uint(cau));
            if (((mv & mu) & 0x1FFull) == 0x1FFull && last_m == ca_m) {
                t_det = t; Pf = t - ca_t;
                break;
            }
        }
        if (t == next_coarse) {
            cav = v; cau = u; ca_m = last_m; ca_t = t;
            next_coarse <<= 1;
        }
        blk5 = (blk5 == 4) ? 0 : (blk5 + 1);

        #pragma unroll
        for (int j = 0; j < 8; ++j) {
            // candidate-I prep from prev-step bits (VALU, off critical path)
            float fI2 = z4v ? (z2v ? I2_11 : I2_01) : (z2v ? I2_10 : I2_00);
            float V0 = z5v ? C0b : C0a;
            float V1 = z5v ? C1b : C1a;
            V0 = is_lane0 ? fI2 : V0;
            float Ib = spec_var1 ? V1 : V0;

            // common izh head (I-independent)
            float t1 = 0.04f * v;
            float t2 = t1 * v;
            float t3 = 5.0f * v;
            float t4 = t2 + t3;
            float t5 = t4 + 140.0f;
            float t6 = t5 - u;
            float bv = b * v;
            float bvu = bv - u;
            float du = ka * bvu;
            float u1 = u + du;
            float u1d = u1 + d;

            // speculative (ballot) tail — fmaf exact (R18-validated)
            float t7b = t6 + Ib;
            float v1b = fmaf(0.25f, t7b, v);   // TAU*DT = 0.25 exactly
            unsigned mlo = (unsigned)__ballot(v1b >= 30.0f);

            // VALU-only resolve: per-lane bit extracts, no SALU crossing
            int z2n = vshr(mlo, 0) & 1;            // LLBN fire
            int sh3 = 1 + z2n;
            int z3n = vshr(mlo, sh3) & 1;          // EBN fire
            int sh45 = 3 + z3n;
            int sh5  = 5 + z3n;
            int z4n = vshr(mlo, sh45) & 1;         // IFN fire (carry)
            int z5n = vshr(mlo, sh5) & 1;          // TN fire (carry/select)
            int selsh = le2 ? l0base : (ge7 ? sh5 : sh3);
            int selb  = vshr(mlo, selsh) & 1;

            // actual tail, recomputed locally with the resolved I
            float Ia = selb ? V1 : V0;
            float t7a = t6 + Ia;
            float v1a = fmaf(0.25f, t7a, v);
            bool fa = (v1a >= 30.0f);
            v = fa ? c : v1a;
            u = fa ? u1d : u1;           // z*d is exactly d or +0.0f

            zb[j] = fa ? 1.0f : 0.0f;
            vb[j] = v;

            z2v = z2n; z4v = z4n; z5v = z5n;
            last_m = mlo;                // uniform; stays scalar
        }
        // batched flush (rows 16B-aligned at t; t % 8 == 0)
        *(float4*)(psp)     = make_float4(zb[0], zb[1], zb[2], zb[3]);
        *(float4*)(psp + 4) = make_float4(zb[4], zb[5], zb[6], zb[7]);
        *(float4*)(pvv)     = make_float4(vb[0], vb[1], vb[2], vb[3]);
        *(float4*)(pvv + 4) = make_float4(vb[4], vb[5], vb[6], vb[7]);
        psp += 8;
        pvv += 8;
    }
    // tail (T not divisible by 8), only when no cycle was detected
    for (; t < T && t_det < 0; ++t) {
        float fI2 = z4v ? (z2v ? I2_11 : I2_01) : (z2v ? I2_10 : I2_00);
        float V0 = z5v ? C0b : C0a;
        float V1 = z5v ? C1b : C1a;
        V0 = is_lane0 ? fI2 : V0;
        float Ib = spec_var1 ? V1 : V0;
        float t1 = 0.04f * v;
        float t2 = t1 * v;
        float t3 = 5.0f * v;
        float t4 = t2 + t3;
        float t5 = t4 + 140.0f;
        float t6 = t5 - u;
        float bv = b * v;
        float bvu = bv - u;
        float du = ka * bvu;
        float u1 = u + du;
        float u1d = u1 + d;
        float t7b = t6 + Ib;
        float v1b = fmaf(0.25f, t7b, v);
        unsigned mlo = (unsigned)__ballot(v1b >= 30.0f);
        int z2n = vshr(mlo, 0) & 1;
        int sh3 = 1 + z2n;
        int z3n = vshr(mlo, sh3) & 1;
        int sh45 = 3 + z3n;
        int sh5  = 5 + z3n;
        int z4n = vshr(mlo, sh45) & 1;
        int z5n = vshr(mlo, sh5) & 1;
        int selsh = le2 ? l0base : (ge7 ? sh5 : sh3);
        int selb  = vshr(mlo, selsh) & 1;
        float Ia = selb ? V1 : V0;
        float t7a = t6 + Ia;
        float v1a = fmaf(0.25f, t7a, v);
        bool fa = (v1a >= 30.0f);
        v = fa ? c : v1a;
        u = fa ? u1d : u1;
        psp[0] = fa ? 1.0f : 0.0f;
        pvv[0] = v;
        ++psp; ++pvv;
        z2v = z2n; z4v = z4n; z5v = z5n;
        last_m = mlo;
    }

    // publish detection result (ws is re-poisoned before every call)
    if (lane == 0) {
        ws[0] = (t_det >= 0) ? 1 : 0;
        ws[1] = t_det;
        ws[2] = Pf;
    }
}

// Fills out[r, t] for t in [t_det, T) with the periodic continuation
// out[r, t_det - P + ((t - t_det) mod P)]. No-op when no cycle was found.
__global__ __launch_bounds__(256) void fill_cycle(float* __restrict__ out,
                                                  const int* __restrict__ ws,
                                                  int T) {
    if (ws[0] == 0) return;
    const int t0 = ws[1];
    const int P  = ws[2];
    const int r  = blockIdx.y;                    // 0..9 (row)
    const float* __restrict__ src = out + (size_t)r * T + (t0 - P);
    float* __restrict__ dst       = out + (size_t)r * T + t0;
    const int n = T - t0;
    for (int i = blockIdx.x * blockDim.x + threadIdx.x; i < n;
         i += gridDim.x * blockDim.x) {
        dst[i] = src[i % P];
    }
}

extern "C" void kernel_launch(void* const* d_in, const int* in_sizes, int n_in,
                              void* d_out, int out_size, void* d_ws, size_t ws_size,
                              hipStream_t stream) {
    const float* mat = (const float*)d_in[0];
    const float* w   = (const float*)d_in[1];
    // out_size = 2 outputs * 5 neurons * T  -> T = out_size/10
    int T = out_size / 10;
    net_sim<<<1, 256, 0, stream>>>(mat, w, (float*)d_out, (int*)d_ws, T);
    dim3 grid(40, 10, 1);
    fill_cycle<<<grid, 256, 0, stream>>>((float*)d_out, (const int*)d_ws, T);
}

// Round 8
// 315.290 us; speedup vs baseline: 1.1052x; 1.1052x over previous
//
#include <hip/hip_runtime.h>

// Exact-order float32 arithmetic: numpy/jax evaluate left-to-right with no
// FMA contraction. hipcc defaults to -ffp-contract=fast, which would change
// rounding -> possible spike-time shift -> large voltage absmax error.
#pragma clang fp contract(off)

// R21: TWO steps per ballot round on the R13-proven substrate.
// Cost model (R16/R19/R20 post-mortems): single resident wave; the per-step
// VALU->SALU->VALU ballot round-trip dominates. R21 pays it once per 2 steps.
// Unlike R17 (failed): NO DPP redistribution, NO mask-derived outputs —
// both steps are RECOMPUTED LOCALLY with resolved I via sel_mask (the
// R13/R18-validated pattern), so every stored value comes from the exact
// validated f32 op sequence.
//
// Lane map (23 lanes of wave 0):
//   step-t speculation (R13 map, ballot bits 0-8):
//     0: LLBN (I2 known from carries)        bit0 = z2(t)
//     1,2: EBN z2-hyp 0/1                    z3(t) = bit(1+z2t)
//     3,4: IFN z3-hyp                        z4(t) = bit(3+z3t)
//     5,6: TN  z3-hyp (z5p carry folded)     z5(t) = bit(5+z3t)
//     7,8: MN  z5-hyp                        z6(t) = bit(7+z5t) (unused)
//   step-t+1 speculation (bits 9-22; each lane cascades its own step-t sim,
//   own fire is hypothesis-consistent; b = 1-(lane&1)):
//     9,10 : LLBN, hyp b=z4(t)               z2(t+1) = bit(9+z4t)
//     11-14: EBN, (a,b)=(z2(t),z2(t+1)), idx=2a+b
//                                            z3(t+1) = bit(11+2*z2t+z2n)
//     15-18: IFN, (a,b)=(z3(t),z3(t+1))      z4(t+1) = bit(15+2*z3t+z3n)
//     19-22: TN,  (a,b)=(z3(t),z3(t+1))      z5(t+1) = bit(19+2*z3t+z3n)
//   (MN step-2 lanes unnecessary: z6 feeds nothing; outputs come from local
//   recompute.)
// Round: spec step t (head+tail) -> cascade spec step t+1 -> ONE ballot
// (bb = lane<9 ? f1 : f2) -> uniform SALU resolve of both steps' bits ->
// recompute step t (I-independent u-chain reused; 2-op v-tail with
// sel_mask(ssel1)) -> recompute step t+1 (full head from finalized state,
// sel_mask(ssel2)) -> buffered stores. Group masks for ssel:
//   GE(EBN)={1,2,11-14}=0x7806  GIT(IFN+TN)={3,4,15-18,5,6,19-22}=0x7F8078
//   GM(MN)={7,8}=0x180.
// Detection (rolling-40 anchor at block tops + Brent pow-2 fallback,
// carries z2/z4/z5 + bitwise v,u over 23 lanes, mask 0x7FFFFF), batched
// float4 flush (duplicate lanes per row store identical values — benign),
// fill_cycle: R13/R18 semantics verbatim. fmaf(0.25,t7,v) exact-fusion
// validated in R18.

__device__ __forceinline__ float sel_mask(float a, float b, unsigned long long m) {
    float r;
    // D = m.bit[lane] ? S1 : S0   (VOP3 v_cndmask with SGPR-pair condition)
    asm("v_cndmask_b32 %0, %1, %2, %3" : "=v"(r) : "v"(a), "v"(b), "s"(m));
    return r;
}

__global__ __launch_bounds__(256) void net_sim(const float* __restrict__ mat,
                                               const float* __restrict__ w,
                                               float* __restrict__ out,
                                               int* __restrict__ ws,
                                               int T) {
    __shared__ double red[256];
    const int tid = threadIdx.x;

    // ---- z_plus = sum(input_mat * w0), f32 products accumulated in f64 ----
    const float w0 = w[0];
    double s = 0.0;
    for (int i = tid; i < 127 * 127; i += 256) {
        float p = mat[i] * w0;   // elementwise product rounded to f32 (as ref)
        s += (double)p;
    }
    red[tid] = s;
    __syncthreads();
    #pragma unroll
    for (int off = 128; off > 0; off >>= 1) {
        if (tid < off) red[tid] += red[tid + off];
        __syncthreads();
    }
    if (tid >= 23) return;   // 23 lanes of wave 0 continue; no more barriers

    const float z_plus = (float)red[0];

    const float w2 = w[2], w3 = w[3], w5 = w[5], w6 = w[6], w7 = w[7],
                w8 = w[8], w9 = w[9], w10 = w[10], w11 = w[11];
    const float zp_w1 = z_plus * w[1];
    const float zp_w4 = z_plus * w[4];

    // Validated constant-I set (R2..R18, absmax 0.0). z*w is exactly +0.0f
    // or w; x + (+0.0f) == x for the values involved.
    const float I2_00 = w2 * (zp_w1 - 0.0f) + w3 * 0.0f;   // (z2p, z4p)
    const float I2_10 = w2 * (zp_w1 - 0.0f) + w3 * 1.0f;
    const float I2_01 = w2 * (zp_w1 - w7)   + w3 * 0.0f;
    const float I2_11 = w2 * (zp_w1 - w7)   + w3 * 1.0f;
    const float I3_0  = zp_w4 + 0.0f * w5;
    const float I3_1  = zp_w4 + 1.0f * w5;
    const float I4_0  = 0.0f * w6;
    const float I4_1  = 1.0f * w6;
    const float I5_00 = w9 * (0.0f * w8) + w10 * 0.0f;     // (z3, z5p)
    const float I5_10 = w9 * (1.0f * w8) + w10 * 0.0f;
    const float I5_01 = w9 * (0.0f * w8) + w10 * 1.0f;
    const float I5_11 = w9 * (1.0f * w8) + w10 * 1.0f;
    const float I6_0  = 0.0f * w11;
    const float I6_1  = 1.0f * w11;

    const int lane = tid;  // 0..22
    // neuron/group id: 0=LLBN 1=EBN 2=IFN 3=TN 4=MN
    const int g = (lane == 0 || lane == 9 || lane == 10) ? 0
                : (lane == 1 || lane == 2 || (lane >= 11 && lane <= 14)) ? 1
                : (lane == 3 || lane == 4 || (lane >= 15 && lane <= 18)) ? 2
                : (lane == 5 || lane == 6 || (lane >= 19 && lane <= 22)) ? 3 : 4;
    const bool isL = (g == 0);
    const bool s2  = (lane >= 9);            // step-t+1 speculation lane
    const int  bbit = s2 ? (1 - (lane & 1)) : 0;   // next-step hypothesis

    // per-group params; ka = float(TAU*DT*a) computed in f64 like Python
    const float ka = isL ? (float)(0.25 * 0.1) : (float)(0.25 * 0.02);
    const float b  = isL ? -0.075f : (g == 3 ? 0.2f : 0.25f);
    const float c  = g <= 1 ? -55.0f : -65.0f;
    const float d  = g == 1 ? 0.05f : 6.0f;
    float v = isL ? -60.0f : (g == 3 ? -70.0f : -64.0f);
    float u = isL ? 4.5f   : (g == 3 ? -14.0f : -16.0f);

    // candidate-I pairs per group: variant0/1, for z5p=0(a)/1(b)
    const float C0a = g == 0 ? I2_00 : g == 1 ? I3_0 : g == 2 ? I4_0
                    : g == 3 ? I5_00 : I6_0;
    const float C0b = g == 3 ? I5_01 : C0a;
    const float C1a = g == 1 ? I3_1 : g == 2 ? I4_1 : g == 3 ? I5_10
                    : g == 4 ? I6_1 : 0.0f;
    const float C1b = g == 3 ? I5_11 : C1a;

    // step-t spec variant bit (a-hyp = 1 lanes)
    const bool sv1 = (lane == 2) | (lane == 4) | (lane == 6) | (lane == 8)
                   | (lane == 13) | (lane == 14) | (lane == 17) | (lane == 18)
                   | (lane == 21) | (lane == 22);

    // step-t+1 spec I constants (lanes 9-22): J = f1 ? JT1 : JT0
    //  LLBN: I2_{f1, b}; EBN: I3_b; IFN: I4_b; TN: I5_{b, f1}
    const float JT0 = !s2 ? 0.0f
                    : g == 0 ? (bbit ? I2_01 : I2_00)
                    : g == 1 ? (bbit ? I3_1 : I3_0)
                    : g == 2 ? (bbit ? I4_1 : I4_0)
                    :          (bbit ? I5_10 : I5_00);   // TN
    const float JT1 = !s2 ? 0.0f
                    : g == 0 ? (bbit ? I2_11 : I2_10)
                    : g == 1 ? (bbit ? I3_1 : I3_0)
                    : g == 2 ? (bbit ? I4_1 : I4_0)
                    :          (bbit ? I5_11 : I5_01);   // TN

    float* __restrict__ psp = out + g * T;           // spikes row
    float* __restrict__ pvv = out + 5 * T + g * T;   // volts row

    int z2c = 0, z4c = 0, z5c = 0;  // carries (z2p,z4p,z5p) — uniform

    // ---- cycle-detection: rolling-40 anchor + Brent pow-2 fallback ----
    const unsigned long long MASKL = 0x7FFFFFull;    // 23 lanes
    float rav = 0.0f, rau = 0.0f; int raz2 = 0, raz4 = 0, raz5 = 0, ra_t = -1;
    float cav = 0.0f, cau = 0.0f; int caz2 = 0, caz4 = 0, caz5 = 0, ca_t = -1;
    int next_coarse = 8;
    int t_det = -1, Pf = 0;
    int blk5 = 0;   // t/8 mod 5; 0 <=> t % 40 == 0

    float zb[8], vb[8];

    int t = 0;
    for (; t + 8 <= T; t += 8) {
        // ---- block top: anchor compares / refresh (R9 semantics) ----
        if (blk5 == 0) {
            if (ra_t >= 0) {
                unsigned long long mv =
                    __ballot(__float_as_uint(v) == __float_as_uint(rav));
                unsigned long long mu =
                    __ballot(__float_as_uint(u) == __float_as_uint(rau));
                if (((mv & mu) & MASKL) == MASKL &&
                    z2c == raz2 && z4c == raz4 && z5c == raz5) {
                    t_det = t; Pf = t - ra_t;   // Pf == 40
                    break;
                }
            }
            if (t) { rav = v; rau = u; raz2 = z2c; raz4 = z4c; raz5 = z5c; ra_t = t; }
        } else if (ca_t >= 0) {
            unsigned long long mv =
                __ballot(__float_as_uint(v) == __float_as_uint(cav));
            unsigned long long mu =
                __ballot(__float_as_uint(u) == __float_as_uint(cau));
            if (((mv & mu) & MASKL) == MASKL &&
                z2c == caz2 && z4c == caz4 && z5c == caz5) {
                t_det = t; Pf = t - ca_t;
                break;
            }
        }
        if (t == next_coarse) {
            cav = v; cau = u; caz2 = z2c; caz4 = z4c; caz5 = z5c; ca_t = t;
            next_coarse <<= 1;
        }
        blk5 = (blk5 == 4) ? 0 : (blk5 + 1);

        #pragma unroll
        for (int j = 0; j < 4; ++j) {      // 4 rounds x 2 steps
            // prep from carries (uniform selects, off critical path)
            float fI2 = z4c ? (z2c ? I2_11 : I2_01) : (z2c ? I2_10 : I2_00);
            float V0s = z5c ? C0b : C0a;
            float V1s = z5c ? C1b : C1a;
            V0s = isL ? fI2 : V0s;
            float Ib1 = sv1 ? V1s : V0s;

            // ---- spec step t (exact izh sequence) ----
            float t1 = 0.04f * v;  float t2 = t1 * v;  float t3 = 5.0f * v;
            float t4 = t2 + t3;    float t5 = t4 + 140.0f; float t6 = t5 - u;
            float bv = b * v;      float bvu = bv - u;  float du = ka * bvu;
            float u1 = u + du;     float u1d = u1 + d;
            float t7 = t6 + Ib1;
            float v1b = fmaf(0.25f, t7, v);
            bool f1 = (v1b >= 30.0f);

            // ---- spec step t+1 (cascade; meaningful on lanes 9-22) ----
            float vs = f1 ? c : v1b;
            float us = f1 ? u1d : u1;
            float J  = f1 ? JT1 : JT0;
            float q1 = 0.04f * vs; float q2 = q1 * vs; float q3 = 5.0f * vs;
            float q4 = q2 + q3;    float q5 = q4 + 140.0f; float q6 = q5 - us;
            float q7 = q6 + J;
            float v2b = fmaf(0.25f, q7, vs);
            bool f2 = (v2b >= 30.0f);

            // ---- one ballot for both steps ----
            bool bbsel = s2 ? f2 : f1;
            unsigned m = (unsigned)__ballot(bbsel);

            // uniform SALU resolve: step t (R13-proven), then step t+1
            int z2t = (int)(m & 1u);
            int z3t = (int)((m >> (1 + z2t)) & 1u);
            int z4t = (int)((m >> (3 + z3t)) & 1u);
            int z5t = (int)((m >> (5 + z3t)) & 1u);
            int z2n = (int)((m >> (9 + z4t)) & 1u);
            int z3n = (int)((m >> (11 + 2 * z2t + z2n)) & 1u);
            int s34 = 2 * z3t + z3n;
            int z4n = (int)((m >> (15 + s34)) & 1u);
            int z5n = (int)((m >> (19 + s34)) & 1u);
            unsigned long long ssel1 =
                  (z2t ? 0x7806ull : 0ull) | (z3t ? 0x7F8078ull : 0ull)
                | (z5t ? 0x180ull : 0ull);
            unsigned long long ssel2 =
                  (z2n ? 0x7806ull : 0ull) | (z3n ? 0x7F8078ull : 0ull)
                | (z5n ? 0x180ull : 0ull);

            // ---- recompute step t: u-chain is I-independent (reuse u1),
            //      v-tail with resolved I (R13 pattern) ----
            float Ia = sel_mask(V0s, V1s, ssel1);
            float t7a = t6 + Ia;
            float v1a = fmaf(0.25f, t7a, v);
            bool fa = (v1a >= 30.0f);
            float vA = fa ? c : v1a;
            float uA = fa ? u1d : u1;
            zb[2 * j] = fa ? 1.0f : 0.0f;
            vb[2 * j] = vA;

            // ---- recompute step t+1 (full head from finalized state) ----
            float fI2p = z4t ? (z2t ? I2_11 : I2_01) : (z2t ? I2_10 : I2_00);
            float V0n = z5t ? C0b : C0a;
            float V1n = z5t ? C1b : C1a;
            V0n = isL ? fI2p : V0n;
            float Ia2 = sel_mask(V0n, V1n, ssel2);
            float r1 = 0.04f * vA; float r2 = r1 * vA; float r3 = 5.0f * vA;
            float r4 = r2 + r3;    float r5 = r4 + 140.0f; float r6 = r5 - uA;
            float bvA = b * vA;    float bvuA = bvA - uA; float duA = ka * bvuA;
            float uB = uA + duA;   float uBd = uB + d;
            float r7 = r6 + Ia2;
            float v2a = fmaf(0.25f, r7, vA);
            bool fa2 = (v2a >= 30.0f);
            v = fa2 ? c : v2a;
            u = fa2 ? uBd : uB;
            zb[2 * j + 1] = fa2 ? 1.0f : 0.0f;
            vb[2 * j + 1] = v;

            z2c = z2n; z4c = z4n; z5c = z5n;
        }
        // batched flush (rows 16B-aligned at t; t % 8 == 0); lanes sharing a
        // row store identical values — benign
        *(float4*)(psp)     = make_float4(zb[0], zb[1], zb[2], zb[3]);
        *(float4*)(psp + 4) = make_float4(zb[4], zb[5], zb[6], zb[7]);
        *(float4*)(pvv)     = make_float4(vb[0], vb[1], vb[2], vb[3]);
        *(float4*)(pvv + 4) = make_float4(vb[4], vb[5], vb[6], vb[7]);
        psp += 8;
        pvv += 8;
    }
    // tail (T not divisible by 8): single-step rounds, only if no cycle
    for (; t < T && t_det < 0; ++t) {
        float fI2 = z4c ? (z2c ? I2_11 : I2_01) : (z2c ? I2_10 : I2_00);
        float V0s = z5c ? C0b : C0a;
        float V1s = z5c ? C1b : C1a;
        V0s = isL ? fI2 : V0s;
        float Ib1 = sv1 ? V1s : V0s;
        float t1 = 0.04f * v;  float t2 = t1 * v;  float t3 = 5.0f * v;
        float t4 = t2 + t3;    float t5 = t4 + 140.0f; float t6 = t5 - u;
        float bv = b * v;      float bvu = bv - u;  float du = ka * bvu;
        float u1 = u + du;     float u1d = u1 + d;
        float t7 = t6 + Ib1;
        float v1b = fmaf(0.25f, t7, v);
        bool f1 = (v1b >= 30.0f);
        unsigned m = (unsigned)__ballot(f1);
        int z2t = (int)(m & 1u);
        int z3t = (int)((m >> (1 + z2t)) & 1u);
        int z4t = (int)((m >> (3 + z3t)) & 1u);
        int z5t = (int)((m >> (5 + z3t)) & 1u);
        unsigned long long ssel1 =
              (z2t ? 0x7806ull : 0ull) | (z3t ? 0x7F8078ull : 0ull)
            | (z5t ? 0x180ull : 0ull);
        float Ia = sel_mask(V0s, V1s, ssel1);
        float t7a = t6 + Ia;
        float v1a = fmaf(0.25f, t7a, v);
        bool fa = (v1a >= 30.0f);
        v = fa ? c : v1a;
        u = fa ? u1d : u1;
        psp[0] = fa ? 1.0f : 0.0f;
        pvv[0] = v;
        ++psp; ++pvv;
        z2c = z2t; z4c = z4t; z5c = z5t;
    }

    // publish detection result (ws is re-poisoned before every call)
    if (lane == 0) {
        ws[0] = (t_det >= 0) ? 1 : 0;
        ws[1] = t_det;
        ws[2] = Pf;
    }
}

// Fills out[r, t] for t in [t_det, T) with the periodic continuation
// out[r, t_det - P + ((t - t_det) mod P)]. No-op when no cycle was found.
__global__ __launch_bounds__(256) void fill_cycle(float* __restrict__ out,
                                                  const int* __restrict__ ws,
                                                  int T) {
    if (ws[0] == 0) return;
    const int t0 = ws[1];
    const int P  = ws[2];
    const int r  = blockIdx.y;                    // 0..9 (row)
    const float* __restrict__ src = out + (size_t)r * T + (t0 - P);
    float* __restrict__ dst       = out + (size_t)r * T + t0;
    const int n = T - t0;
    for (int i = blockIdx.x * blockDim.x + threadIdx.x; i < n;
         i += gridDim.x * blockDim.x) {
        dst[i] = src[i % P];
    }
}

extern "C" void kernel_launch(void* const* d_in, const int* in_sizes, int n_in,
                              void* d_out, int out_size, void* d_ws, size_t ws_size,
                              hipStream_t stream) {
    const float* mat = (const float*)d_in[0];
    const float* w   = (const float*)d_in[1];
    // out_size = 2 outputs * 5 neurons * T  -> T = out_size/10
    int T = out_size / 10;
    net_sim<<<1, 256, 0, stream>>>(mat, w, (float*)d_out, (int*)d_ws, T);
    dim3 grid(40, 10, 1);
    fill_cycle<<<grid, 256, 0, stream>>>((float*)d_out, (const int*)d_ws, T);
}